// Round 2
// baseline (440.432 us; speedup 1.0000x reference)
//
#include <hip/hip_runtime.h>

#define BB 64
#define PP 8732
#define CC 81
#define RPB 128                 // priors (rows) per streaming block
#define SLOTS ((RPB * CC) / 4)  // 2592 float4 slots per full chunk
#define TPB 512                 // threads per kMain block (8 waves)

// ---------- helpers ----------

__device__ __forceinline__ float sl1(float d) {
    d = fabsf(d);
    return d < 1.0f ? 0.5f * d * d : d - 0.5f;
}

// Block reduce (blockDim.x multiple of 64, <=1024). Returns total to ALL threads.
__device__ __forceinline__ float blockReduceF(float v, volatile float* sb) {
    for (int off = 32; off; off >>= 1) v += __shfl_xor(v, off, 64);
    __syncthreads();
    if ((threadIdx.x & 63) == 0) sb[threadIdx.x >> 6] = v;
    __syncthreads();
    float r = 0.0f;
    int nw = blockDim.x >> 6;
    for (int i = 0; i < nw; ++i) r += sb[i];
    return r;
}

__device__ __forceinline__ int blockReduceI(int v, volatile int* sb) {
    for (int off = 32; off; off >>= 1) v += __shfl_xor(v, off, 64);
    __syncthreads();
    if ((threadIdx.x & 63) == 0) sb[threadIdx.x >> 6] = v;
    __syncthreads();
    int r = 0;
    int nw = blockDim.x >> 6;
    for (int i = 0; i < nw; ++i) r += sb[i];
    return r;
}

// ---------- kernel 0: zero accumulators ----------
__global__ void kInit(float* acc, int* numpos, int* ctr) {
    int t = threadIdx.x;
    if (t < 4) acc[t] = 0.0f;
    if (t < BB) numpos[t] = 0;
    if (t == 0) ctr[0] = 0;
}

// ---------- per-slot softmax-denominator piece (unchanged math) ----------
// Slot i (one float4): NON-ATOMIC psum[i] = sum(exp) of the slot's elements
// belonging to owner row r0 = (4i)/81; split slots (rem in {78,79,80}) write
// the remainder to spill[r0+1] (unique writer per row, always overwritten on
// the second tensor pass). Consecutive lanes write consecutive psum addresses.
// No max-subtraction: inputs are N(0,1); sum(exp) < 81*e^6 -- no fp32 overflow.
__device__ __forceinline__ void processSlot(int i, float4 v,
                                            float* psum, float* spill) {
    int f = i << 2;
    int r0 = f / 81;                         // compiler magic-mul
    int rem = f - r0 * 81;
    float e0 = __expf(v.x), e1 = __expf(v.y), e2 = __expf(v.z), e3 = __expf(v.w);
    float t01 = e0 + e1;
    float tot = t01 + e2 + e3;
    float ps = tot;
    if (rem >= 78) {                         // slot crosses into row r0+1
        int ns = 81 - rem;                   // elems belonging to r0: 1..3
        float a = (ns == 1) ? e0 : ((ns == 2) ? t01 : t01 + e2);
        ps = a;
        spill[r0 + 1] = tot - a;             // unique writer per row: no atomic
    }
    psum[i] = ps;
}

// Phase 2: 2 threads per row; row r owns slots [ceil(81r/4), ceil(81(r+1)/4)).
// spill[r] is valid iff r%4 != 0 (row boundary 16B-aligned iff 4 | r).
__device__ __forceinline__ void phase2(float* __restrict__ dst, size_t rowBase,
                                       int nrows, int tid,
                                       const float* psum, const float* spill,
                                       const float* gtval, const int* gtraw) {
    int r = tid >> 1, h = tid & 1;
    if (r < nrows) {
        int i0 = (81 * r + 3) >> 2;
        int i1 = (81 * (r + 1) + 3) >> 2;    // exclusive
        int mid = (i0 + i1 + 1) >> 1;
        int lo = h ? mid : i0;
        int hi = h ? i1 : mid;
        float s = (h == 0 && (r & 3)) ? spill[r] : 0.0f;
        for (int i = lo; i < hi; ++i) s += psum[i];
        s += __shfl_xor(s, 1, 64);           // pair lanes share a wave
        if (h == 0) {
            float lc = __logf(s) - gtval[r];
            dst[rowBase + r] = (gtraw[r] > 0) ? -(lc + 1.0f) : lc;  // positives sign-encoded
        }
    }
}

// ---------- kMain: fused loc-SmoothL1 + per-prior CE for BOTH tensors ----------
// grid = (69, 64), 512 threads. Each block owns 128 rows and processes the T
// conf tile, then the S conf tile, with S's global loads issued BEFORE T's
// phase-2/barriers so memory stays busy during the LDS-reduce phases
// (previously those barriers had zero loads outstanding). Loc work (kA) is
// folded in: the 128 row-owner threads read conft once and handle the ~2%
// positive rows' SmoothL1 sums + the per-batch positive count.
__global__ __launch_bounds__(TPB, 6) void kMain(
        const float* __restrict__ confT, const float* __restrict__ confS,
        const int* __restrict__ conft,
        const float4* __restrict__ locT4, const float4* __restrict__ locS4,
        const float4* __restrict__ loct4,
        float* __restrict__ lcT, float* __restrict__ lcS,
        float* acc, int* numpos) {
    __shared__ float psum[SLOTS];
    __shared__ float spill[RPB];
    __shared__ float gtval[RPB];
    __shared__ int gtraw[RPB];
    __shared__ float fsb[TPB / 64];
    __shared__ int isb[TPB / 64];

    int b = blockIdx.y;
    int p0 = blockIdx.x * RPB;
    int nrows = min(RPB, PP - p0);           // 128, or 28 in the tail block
    int tid = threadIdx.x;
    size_t rowBase = (size_t)b * PP + p0;
    const float* __restrict__ rowT = confT + rowBase * CC;   // 16B-aligned
    const float* __restrict__ rowS = confS + rowBase * CC;
    const float4* __restrict__ gT = (const float4*)rowT;
    const float4* __restrict__ gS = (const float4*)rowS;

    bool hasrow = tid < nrows;
    int g_ = 0;
    if (hasrow) g_ = conft[rowBase + tid];   // issued first: oldest outstanding

    float sT = 0.0f, sS = 0.0f;
    int cnt = 0;

    if (nrows == RPB) {
        // T tile: 2592 = 512*5 + 32 float4 slots.
        float4 v[5];
        #pragma unroll
        for (int k = 0; k < 5; ++k) v[k] = gT[tid + TPB * k];
        float4 vx;
        bool extra = tid < (SLOTS - 5 * TPB);            // tid < 32
        if (extra) vx = gT[5 * TPB + tid];
        // gt logits (re-read; L2-resident) + sparse loc work, both gated on g_.
        float gtvT = 0.0f, gtvS = 0.0f;
        if (hasrow) {
            gtvT = rowT[tid * CC + g_];
            gtvS = rowS[tid * CC + g_];
            if (g_ > 0) {
                size_t idx = rowBase + tid;
                float4 gt = loct4[idx];
                float4 aT = locT4[idx];
                float4 aS = locS4[idx];
                sT = sl1(aT.x - gt.x) + sl1(aT.y - gt.y) + sl1(aT.z - gt.z) + sl1(aT.w - gt.w);
                sS = sl1(aS.x - gt.x) + sl1(aS.y - gt.y) + sl1(aS.z - gt.z) + sl1(aS.w - gt.w);
                cnt = 1;
            }
        }
        #pragma unroll
        for (int k = 0; k < 5; ++k) processSlot(tid + TPB * k, v[k], psum, spill);
        if (extra) processSlot(5 * TPB + tid, vx, psum, spill);
        // Issue S tile loads NOW: they fly during T's barrier + phase 2.
        float4 w[5];
        #pragma unroll
        for (int k = 0; k < 5; ++k) w[k] = gS[tid + TPB * k];
        float4 wx;
        if (extra) wx = gS[5 * TPB + tid];
        if (hasrow) { gtraw[tid] = g_; gtval[tid] = gtvT; }
        __syncthreads();
        phase2(lcT, rowBase, nrows, tid, psum, spill, gtval, gtraw);
        __syncthreads();
        #pragma unroll
        for (int k = 0; k < 5; ++k) processSlot(tid + TPB * k, w[k], psum, spill);
        if (extra) processSlot(5 * TPB + tid, wx, psum, spill);
        if (hasrow) gtval[tid] = gtvS;
        __syncthreads();
        phase2(lcS, rowBase, nrows, tid, psum, spill, gtval, gtraw);
    } else {
        int nq = (nrows * CC) >> 2;          // 567 in the tail block (exact)
        float gtvT = 0.0f, gtvS = 0.0f;
        if (hasrow) {
            gtvT = rowT[tid * CC + g_];
            gtvS = rowS[tid * CC + g_];
            if (g_ > 0) {
                size_t idx = rowBase + tid;
                float4 gt = loct4[idx];
                float4 aT = locT4[idx];
                float4 aS = locS4[idx];
                sT = sl1(aT.x - gt.x) + sl1(aT.y - gt.y) + sl1(aT.z - gt.z) + sl1(aT.w - gt.w);
                sS = sl1(aS.x - gt.x) + sl1(aS.y - gt.y) + sl1(aS.z - gt.z) + sl1(aS.w - gt.w);
                cnt = 1;
            }
        }
        for (int i = tid; i < nq; i += TPB) processSlot(i, gT[i], psum, spill);
        if (hasrow) { gtraw[tid] = g_; gtval[tid] = gtvT; }
        __syncthreads();
        phase2(lcT, rowBase, nrows, tid, psum, spill, gtval, gtraw);
        __syncthreads();
        for (int i = tid; i < nq; i += TPB) processSlot(i, gS[i], psum, spill);
        if (hasrow) gtval[tid] = gtvS;
        __syncthreads();
        phase2(lcS, rowBase, nrows, tid, psum, spill, gtval, gtraw);
    }

    // loc reduction (kA fused): all threads participate uniformly.
    sT = blockReduceF(sT, fsb);
    sS = blockReduceF(sS, fsb);
    cnt = blockReduceI(cnt, isb);
    if (tid == 0) {
        if (sT != 0.0f) atomicAdd(&acc[0], sT);
        if (sS != 0.0f) atomicAdd(&acc[1], sS);
        if (cnt) atomicAdd(&numpos[b], cnt);
    }
}

// ---------- kernel C: hard-negative mining (radix select) + fused finalize ----------
// grid = (2, BB): blockIdx.x selects tensor (0=T -> acc[2], 1=S -> acc[3]).
// Key = (v < 0) ? 0 : bits(v): encoded positives participate as 0.0, bit-exactly
// the reference's where(pos, 0, lc) ranking multiset (lc >= 0 always).
// v3: per-wave private histograms. CE losses are ~2..10, so float top bytes
// concentrate in 1-2 bins -- a single shared hist serialized ~8732 atomics on
// one LDS address per round. 16 per-wave slices cap serialization at 64-way.
// The last block to finish (device atomic counter) computes out[] (kD fused).
__global__ __launch_bounds__(1024) void kC(const float* __restrict__ lcT,
                                           const float* __restrict__ lcS,
                                           const int* __restrict__ numpos,
                                           float* acc, int* ctr,
                                           float* __restrict__ out) {
    __shared__ unsigned keys[PP];
    __shared__ int whist[16 * 256];
    __shared__ int hist[256];
    __shared__ float fsb[16];
    __shared__ int isb[16];
    __shared__ int selBin, selAbove, lastFlag;
    int b = blockIdx.y;
    int tid = threadIdx.x;
    const float* src = ((blockIdx.x == 0) ? lcT : lcS) + (size_t)b * PP;

    float posSum = 0.0f;
    for (int i = tid; i < PP; i += 1024) {
        float v = src[i];
        keys[i] = (v < 0.0f) ? 0u : __float_as_uint(v);
        if (v < 0.0f) posSum += (-v - 1.0f);
    }
    posSum = blockReduceF(posSum, fsb);   // internal syncs fence keys[] writes

    int np = numpos[b];
    int k = min(3 * np, PP - 1);
    float mined = 0.0f;
    if (k > 0) {
        unsigned prefix = 0;
        int kk = k;
        int wid = tid >> 6;
        for (int round = 0; round < 4; ++round) {
            int shift = 24 - 8 * round;
            for (int i = tid; i < 16 * 256; i += 1024) whist[i] = 0;
            __syncthreads();
            for (int i = tid; i < PP; i += 1024) {
                unsigned key = keys[i];
                bool match = (round == 0) || ((key >> (shift + 8)) == prefix);
                if (match) atomicAdd(&whist[(wid << 8) | ((key >> shift) & 0xFF)], 1);
            }
            __syncthreads();
            if (tid < 256) {
                int h2 = 0;
                #pragma unroll
                for (int w = 0; w < 16; ++w) h2 += whist[(w << 8) | tid];
                hist[tid] = h2;
            }
            __syncthreads();
            // parallel inclusive suffix scan: hist[t] <- sum_{j>=t} hist[j]
            for (int d = 1; d < 256; d <<= 1) {
                int v2 = 0;
                if (tid < 256) v2 = hist[tid] + ((tid + d < 256) ? hist[tid + d] : 0);
                __syncthreads();
                if (tid < 256) hist[tid] = v2;
                __syncthreads();
            }
            if (tid < 256) {
                int above = (tid < 255) ? hist[tid + 1] : 0;
                if (above < kk && hist[tid] >= kk) {   // unique bin
                    selBin = tid;
                    selAbove = above;
                }
            }
            __syncthreads();
            prefix = (prefix << 8) | (unsigned)selBin;
            kk -= selAbove;
            __syncthreads();
        }
        // prefix = bit pattern of the exact k-th largest key
        int c = 0;
        float s = 0.0f;
        for (int i = tid; i < PP; i += 1024) {
            unsigned key = keys[i];
            if (key > prefix) { c += 1; s += __uint_as_float(key); }
        }
        c = blockReduceI(c, isb);
        s = blockReduceF(s, fsb);
        mined = s + (float)(k - c) * __uint_as_float(prefix);
    }
    if (tid == 0) {
        atomicAdd(&acc[(blockIdx.x == 0) ? 2 : 3], posSum + mined);
        __threadfence();                       // our acc write visible before ctr
        int old = atomicAdd(ctr, 1);           // device-scope
        lastFlag = (old == 2 * BB - 1) ? 1 : 0;
    }
    __syncthreads();
    if (lastFlag) {                            // fused kD: last block finalizes
        __threadfence();
        int v = 0;
        if (tid < BB)
            v = __hip_atomic_load(&numpos[tid], __ATOMIC_RELAXED, __HIP_MEMORY_SCOPE_AGENT);
        if (tid < 64)
            for (int off = 32; off; off >>= 1) v += __shfl_xor(v, off, 64);
        if (tid == 0) {
            float N = (float)v;
            float a0 = __hip_atomic_load(&acc[0], __ATOMIC_RELAXED, __HIP_MEMORY_SCOPE_AGENT);
            float a1 = __hip_atomic_load(&acc[1], __ATOMIC_RELAXED, __HIP_MEMORY_SCOPE_AGENT);
            float a2 = __hip_atomic_load(&acc[2], __ATOMIC_RELAXED, __HIP_MEMORY_SCOPE_AGENT);
            float a3 = __hip_atomic_load(&acc[3], __ATOMIC_RELAXED, __HIP_MEMORY_SCOPE_AGENT);
            out[0] = a0 / N;  // loss_lT / N
            out[1] = a2 / N;  // loss_cT / N
            out[2] = a1 / N;  // loss_lS / N
            out[3] = a3 / N;  // loss_cS / N
        }
    }
}

// ---------- launch ----------
extern "C" void kernel_launch(void* const* d_in, const int* in_sizes, int n_in,
                              void* d_out, int out_size, void* d_ws, size_t ws_size,
                              hipStream_t stream) {
    const float* locT  = (const float*)d_in[0];
    const float* confT = (const float*)d_in[1];
    const float* locS  = (const float*)d_in[2];
    const float* confS = (const float*)d_in[3];
    const float* loct  = (const float*)d_in[4];
    const int*   conft = (const int*)d_in[5];
    float* out = (float*)d_out;

    float* lcT = (float*)d_ws;
    float* lcS = lcT + (size_t)BB * PP;
    float* acc = lcS + (size_t)BB * PP;
    int* numpos = (int*)(acc + 4);
    int* ctr = numpos + BB;

    kInit<<<1, 64, 0, stream>>>(acc, numpos, ctr);

    dim3 gM((PP + RPB - 1) / RPB, BB);
    kMain<<<gM, TPB, 0, stream>>>(confT, confS, conft,
                                  (const float4*)locT, (const float4*)locS,
                                  (const float4*)loct, lcT, lcS, acc, numpos);

    dim3 gC(2, BB);
    kC<<<gC, 1024, 0, stream>>>(lcT, lcS, numpos, acc, ctr, out);
}

// Round 3
// 425.395 us; speedup vs baseline: 1.0353x; 1.0353x over previous
//
#include <hip/hip_runtime.h>

#define BB 64
#define PP 8732
#define CC 81
#define RPW 16                    // rows per wave
#define WSLOTS ((RPW * CC) / 4)   // 324 float4 slots per wave tile
#define WSTRIDE (WSLOTS + RPW)    // 340 floats of LDS per wave (psum + spill)
#define WPB 4                     // waves per block
#define ROWS_PB (RPW * WPB)       // 64 rows per block

// ---------- helpers ----------

__device__ __forceinline__ float sl1(float d) {
    d = fabsf(d);
    return d < 1.0f ? 0.5f * d * d : d - 0.5f;
}

// Block reduce (blockDim.x multiple of 64, <=1024). Returns total to ALL threads.
__device__ __forceinline__ float blockReduceF(float v, volatile float* sb) {
    for (int off = 32; off; off >>= 1) v += __shfl_xor(v, off, 64);
    __syncthreads();
    if ((threadIdx.x & 63) == 0) sb[threadIdx.x >> 6] = v;
    __syncthreads();
    float r = 0.0f;
    int nw = blockDim.x >> 6;
    for (int i = 0; i < nw; ++i) r += sb[i];
    return r;
}

__device__ __forceinline__ int blockReduceI(int v, volatile int* sb) {
    for (int off = 32; off; off >>= 1) v += __shfl_xor(v, off, 64);
    __syncthreads();
    if ((threadIdx.x & 63) == 0) sb[threadIdx.x >> 6] = v;
    __syncthreads();
    int r = 0;
    int nw = blockDim.x >> 6;
    for (int i = 0; i < nw; ++i) r += sb[i];
    return r;
}

// ---------- kernel 0: zero accumulators ----------
__global__ void kInit(float* acc, int* numpos, int* ctr, float* locPart) {
    int t = threadIdx.x;
    if (t < 4) acc[t] = 0.0f;
    if (t < BB) { numpos[t] = 0; locPart[t] = 0.0f; locPart[BB + t] = 0.0f; }
    if (t == 0) ctr[0] = 0;
}

// ---------- per-slot softmax-denominator piece ----------
// Slot i (wave-local, one float4): psum[i] = sum(exp) of the slot's elements
// belonging to owner (wave-local) row r0 = (4i)/81; split slots (rem 78..80)
// write the remainder to spill[r0+1] (unique writer per row). r0+1 <= 15
// always: the wave tile is 1296 floats, divisible by 4, so the last slot never
// crosses out of the tile. spill[r] is written iff r%4 != 0.
// No max-subtraction: inputs are N(0,1); sum(exp) < 81*e^6 -- no fp32 overflow.
__device__ __forceinline__ void processSlot(int i, float4 v,
                                            float* psum, float* spill) {
    int f = i << 2;
    int r0 = f / 81;                         // compiler magic-mul
    int rem = f - r0 * 81;
    float e0 = __expf(v.x), e1 = __expf(v.y), e2 = __expf(v.z), e3 = __expf(v.w);
    float t01 = e0 + e1;
    float tot = t01 + e2 + e3;
    float ps = tot;
    if (rem >= 78) {                         // slot crosses into row r0+1
        int ns = 81 - rem;                   // elems belonging to r0: 1..3
        float a = (ns == 1) ? e0 : ((ns == 2) ? t01 : t01 + e2);
        ps = a;
        spill[r0 + 1] = tot - a;
    }
    psum[i] = ps;
}

// ---------- kStream: wave-autonomous CE + fused loc-SmoothL1 ----------
// grid = (137, 64, 2), 256 threads (4 waves). Each WAVE owns 16 rows of one
// (batch, tensor) tile and never synchronizes with other waves: the
// psum-write -> psum-read dependency is intra-wave (lgkmcnt only, no
// __syncthreads anywhere). This removes the phase-lockstep that capped rounds
// 0-2 at ~2.2-2.9 TB/s aggregate: every resident wave is an independent
// load-burst/compute stream, so memory stays busy continuously.
// Wave tile: 16*81 = 1296 floats = 324 float4 slots, 16B-aligned for any
// (b, row0) since b*PP*81 and row0*81 are divisible by 4 (row0 % 16 == 0).
// gt label/logit travel lane r -> lane 4r via __shfl (no LDS, no barrier).
// Loc work rides on z==0: conft is already loaded; positives (~2%) gather 3
// float4s; per-wave shfl reduce + conditional atomics to PER-BATCH partials
// (~150 atomics/address over the whole kernel -- negligible contention).
__global__ __launch_bounds__(256, 8) void kStream(
        const float* __restrict__ confT, const float* __restrict__ confS,
        const int* __restrict__ conft,
        const float4* __restrict__ locT4, const float4* __restrict__ locS4,
        const float4* __restrict__ loct4,
        float* __restrict__ lcT, float* __restrict__ lcS,
        float* __restrict__ locPart, int* __restrict__ numpos) {
    __shared__ float lds[WPB * WSTRIDE];
    int b = blockIdx.y;
    int z = blockIdx.z;
    int tid = threadIdx.x;
    int w = tid >> 6, lane = tid & 63;
    int row0 = blockIdx.x * ROWS_PB + w * RPW;
    int nr = min(RPW, PP - row0);            // 16 usually; 12/0 in tail waves
    const float* __restrict__ conf = z ? confS : confT;
    float* __restrict__ dst = z ? lcS : lcT;
    float* psum = lds + w * WSTRIDE;
    float* spill = psum + WSLOTS;

    float sT = 0.0f, sS = 0.0f;
    int cnt = 0;
    int g_ = 0;

    if (nr > 0) {
        size_t rowBase = (size_t)b * PP + row0;
        const float* __restrict__ rowp = conf + rowBase * (size_t)CC;
        const float4* __restrict__ g4 = (const float4*)rowp;
        bool hasrow = lane < nr;
        if (hasrow) g_ = conft[rowBase + lane];   // oldest outstanding load
        float gtv = 0.0f;

        if (nr == RPW) {
            // 324 = 64*5 + 4: batch the loads, then the gt gather (L2-hit:
            // the line is being streamed by this very wave).
            float4 v0 = g4[lane];
            float4 v1 = g4[lane + 64];
            float4 v2 = g4[lane + 128];
            float4 v3 = g4[lane + 192];
            float4 v4 = g4[lane + 256];
            float4 vx;
            bool extra = lane < (WSLOTS - 320);   // lane < 4
            if (extra) vx = g4[320 + lane];
            if (hasrow) gtv = rowp[lane * CC + g_];
            processSlot(lane,       v0, psum, spill);
            processSlot(lane + 64,  v1, psum, spill);
            processSlot(lane + 128, v2, psum, spill);
            processSlot(lane + 192, v3, psum, spill);
            processSlot(lane + 256, v4, psum, spill);
            if (extra) processSlot(320 + lane, vx, psum, spill);
        } else {
            int nq = (nr * CC) >> 2;              // nr%4==0 in all tails
            for (int i = lane; i < nq; i += 64)
                processSlot(i, g4[i], psum, spill);
            if (hasrow) gtv = rowp[lane * CC + g_];
        }

        // Fused loc work (z==0 only): v-regs are dead here, regs get reused.
        if (z == 0 && hasrow && g_ > 0) {
            size_t idx = rowBase + lane;
            float4 gt = loct4[idx];
            float4 aT = locT4[idx];
            float4 aS = locS4[idx];
            sT = sl1(aT.x - gt.x) + sl1(aT.y - gt.y) + sl1(aT.z - gt.z) + sl1(aT.w - gt.w);
            sS = sl1(aS.x - gt.x) + sl1(aS.y - gt.y) + sl1(aS.z - gt.z) + sl1(aS.w - gt.w);
            cnt = 1;
        }

        // Intra-wave fence: all psum/spill writes complete before the reduce.
        asm volatile("s_waitcnt lgkmcnt(0)" ::: "memory");
        __builtin_amdgcn_sched_barrier(0);

        // Reduce: 4 lanes per row. Row r owns slots [ceil(81r/4), ceil(81(r+1)/4)).
        int r = lane >> 2, h = lane & 3;
        float gv = __shfl(gtv, r, 64);            // lane r -> lanes 4r..4r+3
        int   gr = __shfl(g_,  r, 64);
        if (r < nr) {
            int i0 = (81 * r + 3) >> 2;
            int i1 = (81 * (r + 1) + 3) >> 2;     // exclusive
            float s = (h == 0 && (r & 3)) ? spill[r] : 0.0f;
            for (int i = i0 + h; i < i1; i += 4) s += psum[i];
            s += __shfl_xor(s, 1, 64);
            s += __shfl_xor(s, 2, 64);
            if (h == 0) {
                float lc = __logf(s) - gv;
                dst[rowBase + r] = (gr > 0) ? -(lc + 1.0f) : lc;  // positives sign-encoded
            }
        }
    }

    if (z == 0) {
        // Per-wave loc reduce; one conditional atomic triple per wave.
        for (int off = 32; off; off >>= 1) {
            sT  += __shfl_xor(sT,  off, 64);
            sS  += __shfl_xor(sS,  off, 64);
            cnt += __shfl_xor(cnt, off, 64);
        }
        if (lane == 0 && cnt) {
            atomicAdd(&locPart[b], sT);
            atomicAdd(&locPart[BB + b], sS);
            atomicAdd(&numpos[b], cnt);
        }
    }
}

// ---------- kernel C: hard-negative mining (radix select) + fused finalize ----------
// grid = (2, BB): blockIdx.x selects tensor (0=T -> acc[2], 1=S -> acc[3]).
// Key = (v < 0) ? 0 : bits(v): encoded positives participate as 0.0, bit-exactly
// the reference's where(pos, 0, lc) ranking multiset (lc >= 0 always; sum of
// top-k is tie-order independent).
// Per-wave private histograms cap hot-bin atomic serialization at 64-way.
// Suffix scan is now 2 barriers (wave shuffle scan) instead of 16.
// The last block to finish (device atomic counter) computes out[] (kD fused).
__global__ __launch_bounds__(1024) void kC(const float* __restrict__ lcT,
                                           const float* __restrict__ lcS,
                                           const int* __restrict__ numpos,
                                           const float* __restrict__ locPart,
                                           float* acc, int* ctr,
                                           float* __restrict__ out) {
    __shared__ unsigned keys[PP];
    __shared__ int whist[16 * 256];
    __shared__ int hist[256];
    __shared__ float fsb[16];
    __shared__ int isb[16];
    __shared__ int selBin, selAbove, lastFlag, wsum[4];
    int b = blockIdx.y;
    int tid = threadIdx.x;
    int lane = tid & 63;
    const float* src = ((blockIdx.x == 0) ? lcT : lcS) + (size_t)b * PP;

    float posSum = 0.0f;
    for (int i = tid; i < PP; i += 1024) {
        float v = src[i];
        keys[i] = (v < 0.0f) ? 0u : __float_as_uint(v);
        if (v < 0.0f) posSum += (-v - 1.0f);
    }
    posSum = blockReduceF(posSum, fsb);   // internal syncs fence keys[] writes

    int np = numpos[b];
    int k = min(3 * np, PP - 1);
    float mined = 0.0f;
    if (k > 0) {
        unsigned prefix = 0;
        int kk = k;
        int wid = tid >> 6;
        for (int round = 0; round < 4; ++round) {
            int shift = 24 - 8 * round;
            for (int i = tid; i < 16 * 256; i += 1024) whist[i] = 0;
            __syncthreads();
            for (int i = tid; i < PP; i += 1024) {
                unsigned key = keys[i];
                bool match = (round == 0) || ((key >> (shift + 8)) == prefix);
                if (match) atomicAdd(&whist[(wid << 8) | ((key >> shift) & 0xFF)], 1);
            }
            __syncthreads();
            if (tid < 256) {
                int h2 = 0;
                #pragma unroll
                for (int w = 0; w < 16; ++w) h2 += whist[(w << 8) | tid];
                hist[tid] = h2;
            }
            __syncthreads();
            // inclusive suffix scan of hist[256]: wave shuffle scan, 2 barriers.
            int x = (tid < 256) ? hist[tid] : 0;
            for (int d = 1; d < 64; d <<= 1) {
                int y = __shfl_down(x, d, 64);
                if (lane + d < 64) x += y;
            }
            if (tid < 256 && lane == 0) wsum[tid >> 6] = x;
            __syncthreads();
            if (tid < 256) {
                int wv = tid >> 6;
                int add = 0;
                if (wv < 3) add += wsum[wv + 1];
                if (wv < 2) add += wsum[wv + 2];
                if (wv < 1) add += wsum[wv + 3];
                int sfx = x + add;                 // sum_{j>=tid} hist[j]
                hist[tid] = sfx;
            }
            __syncthreads();
            if (tid < 256) {
                int above = (tid < 255) ? hist[tid + 1] : 0;
                if (above < kk && hist[tid] >= kk) {   // unique bin
                    selBin = tid;
                    selAbove = above;
                }
            }
            __syncthreads();
            prefix = (prefix << 8) | (unsigned)selBin;
            kk -= selAbove;
            __syncthreads();
        }
        // prefix = bit pattern of the exact k-th largest key
        int c = 0;
        float s = 0.0f;
        for (int i = tid; i < PP; i += 1024) {
            unsigned key = keys[i];
            if (key > prefix) { c += 1; s += __uint_as_float(key); }
        }
        c = blockReduceI(c, isb);
        s = blockReduceF(s, fsb);
        mined = s + (float)(k - c) * __uint_as_float(prefix);
    }
    if (tid == 0) {
        atomicAdd(&acc[(blockIdx.x == 0) ? 2 : 3], posSum + mined);
        __threadfence();                       // our acc write visible before ctr
        int old = atomicAdd(ctr, 1);           // device-scope
        lastFlag = (old == 2 * BB - 1) ? 1 : 0;
    }
    __syncthreads();
    if (lastFlag) {                            // fused finalize: last block
        __threadfence();
        int v = 0;
        float pT = 0.0f, pS = 0.0f;
        if (tid < BB) {
            v  = __hip_atomic_load(&numpos[tid], __ATOMIC_RELAXED, __HIP_MEMORY_SCOPE_AGENT);
            pT = __hip_atomic_load(&locPart[tid], __ATOMIC_RELAXED, __HIP_MEMORY_SCOPE_AGENT);
            pS = __hip_atomic_load(&locPart[BB + tid], __ATOMIC_RELAXED, __HIP_MEMORY_SCOPE_AGENT);
        }
        if (tid < 64) {
            for (int off = 32; off; off >>= 1) {
                v  += __shfl_xor(v,  off, 64);
                pT += __shfl_xor(pT, off, 64);
                pS += __shfl_xor(pS, off, 64);
            }
        }
        if (tid == 0) {
            float N = (float)v;
            float a2 = __hip_atomic_load(&acc[2], __ATOMIC_RELAXED, __HIP_MEMORY_SCOPE_AGENT);
            float a3 = __hip_atomic_load(&acc[3], __ATOMIC_RELAXED, __HIP_MEMORY_SCOPE_AGENT);
            out[0] = pT / N;  // loss_lT / N
            out[1] = a2 / N;  // loss_cT / N
            out[2] = pS / N;  // loss_lS / N
            out[3] = a3 / N;  // loss_cS / N
        }
    }
}

// ---------- launch ----------
extern "C" void kernel_launch(void* const* d_in, const int* in_sizes, int n_in,
                              void* d_out, int out_size, void* d_ws, size_t ws_size,
                              hipStream_t stream) {
    const float* locT  = (const float*)d_in[0];
    const float* confT = (const float*)d_in[1];
    const float* locS  = (const float*)d_in[2];
    const float* confS = (const float*)d_in[3];
    const float* loct  = (const float*)d_in[4];
    const int*   conft = (const int*)d_in[5];
    float* out = (float*)d_out;

    float* lcT = (float*)d_ws;
    float* lcS = lcT + (size_t)BB * PP;
    float* acc = lcS + (size_t)BB * PP;
    int* numpos = (int*)(acc + 4);
    int* ctr = numpos + BB;
    float* locPart = (float*)(ctr + 1);

    kInit<<<1, 64, 0, stream>>>(acc, numpos, ctr, locPart);

    dim3 gS((PP + ROWS_PB - 1) / ROWS_PB, BB, 2);   // (137, 64, 2)
    kStream<<<gS, 256, 0, stream>>>(confT, confS, conft,
                                    (const float4*)locT, (const float4*)locS,
                                    (const float4*)loct, lcT, lcS,
                                    locPart, numpos);

    dim3 gC(2, BB);
    kC<<<gC, 1024, 0, stream>>>(lcT, lcS, numpos, locPart, acc, ctr, out);
}

// Round 4
// 416.975 us; speedup vs baseline: 1.0563x; 1.0202x over previous
//
#include <hip/hip_runtime.h>

#define BB 64
#define PP 8732
#define CC 81
#define RPW 16                    // rows per wave
#define WSLOTS ((RPW * CC) / 4)   // 324 float4 slots per wave tile
#define WSTRIDE (WSLOTS + RPW)    // 340 floats of LDS per wave (psum + spill)
#define WPB 4                     // waves per block
#define ROWS_PB (RPW * WPB)       // 64 rows per block

// ---------- helpers ----------

__device__ __forceinline__ float sl1(float d) {
    d = fabsf(d);
    return d < 1.0f ? 0.5f * d * d : d - 0.5f;
}

// Block reduce (blockDim.x multiple of 64, <=1024). Returns total to ALL threads.
__device__ __forceinline__ float blockReduceF(float v, volatile float* sb) {
    for (int off = 32; off; off >>= 1) v += __shfl_xor(v, off, 64);
    __syncthreads();
    if ((threadIdx.x & 63) == 0) sb[threadIdx.x >> 6] = v;
    __syncthreads();
    float r = 0.0f;
    int nw = blockDim.x >> 6;
    for (int i = 0; i < nw; ++i) r += sb[i];
    return r;
}

__device__ __forceinline__ int blockReduceI(int v, volatile int* sb) {
    for (int off = 32; off; off >>= 1) v += __shfl_xor(v, off, 64);
    __syncthreads();
    if ((threadIdx.x & 63) == 0) sb[threadIdx.x >> 6] = v;
    __syncthreads();
    int r = 0;
    int nw = blockDim.x >> 6;
    for (int i = 0; i < nw; ++i) r += sb[i];
    return r;
}

// ---------- kernel 0: zero accumulators ----------
__global__ void kInit(float* acc, int* numpos, int* ctr, float* locPart) {
    int t = threadIdx.x;
    if (t < 4) acc[t] = 0.0f;
    if (t < BB) { numpos[t] = 0; locPart[t] = 0.0f; locPart[BB + t] = 0.0f; }
    if (t == 0) ctr[0] = 0;
}

// ---------- per-slot softmax-denominator piece ----------
// Slot i (wave-local, one float4): psum[i] = sum(exp) of the slot's elements
// belonging to owner (wave-local) row r0 = (4i)/81; split slots (rem 78..80)
// write the remainder to spill[r0+1] (unique writer per row). The wave tile is
// 1296 floats (divisible by 4), so the last slot never crosses out of the
// tile. spill[r] is written iff r%4 != 0.
// No max-subtraction: inputs are N(0,1); sum(exp) < 81*e^6 -- no fp32 overflow.
__device__ __forceinline__ void processSlot(int i, float4 v,
                                            float* psum, float* spill) {
    int f = i << 2;
    int r0 = f / 81;                         // compiler magic-mul
    int rem = f - r0 * 81;
    float e0 = __expf(v.x), e1 = __expf(v.y), e2 = __expf(v.z), e3 = __expf(v.w);
    float t01 = e0 + e1;
    float tot = t01 + e2 + e3;
    float ps = tot;
    if (rem >= 78) {                         // slot crosses into row r0+1
        int ns = 81 - rem;                   // elems belonging to r0: 1..3
        float a = (ns == 1) ? e0 : ((ns == 2) ? t01 : t01 + e2);
        ps = a;
        spill[r0 + 1] = tot - a;
    }
    psum[i] = ps;
}

// Wave-level row reduce + store: 4 lanes per row; row r owns slots
// [ceil(81r/4), ceil(81(r+1)/4)). gt label/logit travel lane r -> lanes 4r+h
// via __shfl (no LDS, no barrier). Positives sign-encoded for kC.
__device__ __forceinline__ void waveReduceStore(float* __restrict__ dst,
                                                size_t rowBase, int nr, int lane,
                                                const float* psum,
                                                const float* spill,
                                                float gtv, int g_) {
    int r = lane >> 2, h = lane & 3;
    float gv = __shfl(gtv, r, 64);
    int   gr = __shfl(g_,  r, 64);
    if (r < nr) {
        int i0 = (81 * r + 3) >> 2;
        int i1 = (81 * (r + 1) + 3) >> 2;    // exclusive
        float s = (h == 0 && (r & 3)) ? spill[r] : 0.0f;
        for (int i = i0 + h; i < i1; i += 4) s += psum[i];
        s += __shfl_xor(s, 1, 64);
        s += __shfl_xor(s, 2, 64);
        if (h == 0) {
            float lc = __logf(s) - gv;
            dst[rowBase + r] = (gr > 0) ? -(lc + 1.0f) : lc;
        }
    }
}

// ---------- kStream: wave-autonomous CE (both tensors) + fused loc-SmoothL1 ----
// grid = (137, 64), 256 threads (4 waves). Each WAVE owns 16 rows and handles
// BOTH tensors; no __syncthreads anywhere (psum deps are intra-wave).
//
// v4 fix (the round-3 lesson): VGPR_Count=24 proved the compiler SERIALIZED
// the load batch (20 payload regs can't fit in 24 total) -- ~2 loads in
// flight/wave -> 1.3 TB/s. Now the ENTIRE batch (conft + 6 T + 6 S float4s +
// 2 gt logits, ~15 loads) is issued up front with sched_barrier(0) placed
// IMMEDIATELY AFTER the loads (R3 had it after processing, where it pinned
// nothing). S-loads stay in flight through T's exp/reduce phase (async-split).
// launch_bounds(256,6): 85-VGPR cap fits the ~70-reg batch at 24 waves/CU.
// In-flight target: 24 waves x ~10 x 16B = 3.8 KB/CU >= the ~2.5 KB needed
// for the 6.3 TB/s streaming ceiling at ~250 cy effective latency.
// Loc gathers (2% of rows) moved to the end: short register liveness.
__global__ __launch_bounds__(256, 6) void kStream(
        const float* __restrict__ confT, const float* __restrict__ confS,
        const int* __restrict__ conft,
        const float4* __restrict__ locT4, const float4* __restrict__ locS4,
        const float4* __restrict__ loct4,
        float* __restrict__ lcT, float* __restrict__ lcS,
        float* __restrict__ locPart, int* __restrict__ numpos) {
    __shared__ float lds[WPB * WSTRIDE];
    int b = blockIdx.y;
    int tid = threadIdx.x;
    int w = tid >> 6, lane = tid & 63;
    int row0 = blockIdx.x * ROWS_PB + w * RPW;
    int nr = min(RPW, PP - row0);            // 16 usually; 12 in the one tail wave
    float* psum = lds + w * WSTRIDE;
    float* spill = psum + WSLOTS;

    float sT = 0.0f, sS = 0.0f;
    int cnt = 0;
    int g_ = 0;
    bool hasrow = false;

    if (nr > 0) {
        size_t rowBase = (size_t)b * PP + row0;
        const float* __restrict__ rowT = confT + rowBase * (size_t)CC;
        const float* __restrict__ rowS = confS + rowBase * (size_t)CC;
        const float4* __restrict__ gT4 = (const float4*)rowT;   // 16B-aligned
        const float4* __restrict__ gS4 = (const float4*)rowS;
        hasrow = lane < nr;

        if (nr == RPW) {
            // ---- full load batch: issue EVERYTHING, then pin with sched_barrier.
            if (hasrow) g_ = conft[rowBase + lane];              // oldest load
            float4 t0 = gT4[lane];
            float4 t1 = gT4[lane + 64];
            float4 t2 = gT4[lane + 128];
            float4 t3 = gT4[lane + 192];
            float4 t4 = gT4[lane + 256];
            float4 tx;
            bool extra = lane < (WSLOTS - 320);                  // lane < 4
            if (extra) tx = gT4[320 + lane];
            float4 s0 = gS4[lane];
            float4 s1 = gS4[lane + 64];
            float4 s2 = gS4[lane + 128];
            float4 s3 = gS4[lane + 192];
            float4 s4 = gS4[lane + 256];
            float4 sx;
            if (extra) sx = gS4[320 + lane];
            float gtvT = 0.0f, gtvS = 0.0f;
            if (hasrow) {                                        // L2-hit re-reads
                gtvT = rowT[lane * CC + g_];
                gtvS = rowS[lane * CC + g_];
            }
            __builtin_amdgcn_sched_barrier(0);   // all loads issued before any VALU

            // ---- T phase (S loads still in flight)
            processSlot(lane,       t0, psum, spill);
            processSlot(lane + 64,  t1, psum, spill);
            processSlot(lane + 128, t2, psum, spill);
            processSlot(lane + 192, t3, psum, spill);
            processSlot(lane + 256, t4, psum, spill);
            if (extra) processSlot(320 + lane, tx, psum, spill);
            asm volatile("s_waitcnt lgkmcnt(0)" ::: "memory");
            __builtin_amdgcn_sched_barrier(0);
            waveReduceStore(lcT, rowBase, nr, lane, psum, spill, gtvT, g_);

            // ---- S phase (same psum region; same-wave LDS ops are in-order)
            processSlot(lane,       s0, psum, spill);
            processSlot(lane + 64,  s1, psum, spill);
            processSlot(lane + 128, s2, psum, spill);
            processSlot(lane + 192, s3, psum, spill);
            processSlot(lane + 256, s4, psum, spill);
            if (extra) processSlot(320 + lane, sx, psum, spill);
            asm volatile("s_waitcnt lgkmcnt(0)" ::: "memory");
            __builtin_amdgcn_sched_barrier(0);
            waveReduceStore(lcS, rowBase, nr, lane, psum, spill, gtvS, g_);
        } else {
            // tail wave (nr == 12, one per batch): simple looped path.
            int nq = (nr * CC) >> 2;                             // 243, exact
            if (hasrow) g_ = conft[rowBase + lane];
            for (int i = lane; i < nq; i += 64)
                processSlot(i, gT4[i], psum, spill);
            float gtvT = hasrow ? rowT[lane * CC + g_] : 0.0f;
            asm volatile("s_waitcnt lgkmcnt(0)" ::: "memory");
            __builtin_amdgcn_sched_barrier(0);
            waveReduceStore(lcT, rowBase, nr, lane, psum, spill, gtvT, g_);
            for (int i = lane; i < nq; i += 64)
                processSlot(i, gS4[i], psum, spill);
            float gtvS = hasrow ? rowS[lane * CC + g_] : 0.0f;
            asm volatile("s_waitcnt lgkmcnt(0)" ::: "memory");
            __builtin_amdgcn_sched_barrier(0);
            waveReduceStore(lcS, rowBase, nr, lane, psum, spill, gtvS, g_);
        }

        // ---- fused loc work, issued late (short liveness; ~28% of waves hit)
        if (hasrow && g_ > 0) {
            size_t idx = rowBase + lane;
            float4 gt = loct4[idx];
            float4 aT = locT4[idx];
            float4 aS = locS4[idx];
            sT = sl1(aT.x - gt.x) + sl1(aT.y - gt.y) + sl1(aT.z - gt.z) + sl1(aT.w - gt.w);
            sS = sl1(aS.x - gt.x) + sl1(aS.y - gt.y) + sl1(aS.z - gt.z) + sl1(aS.w - gt.w);
            cnt = 1;
        }
    }

    // Per-wave loc reduce; one conditional atomic triple per wave.
    for (int off = 32; off; off >>= 1) {
        sT  += __shfl_xor(sT,  off, 64);
        sS  += __shfl_xor(sS,  off, 64);
        cnt += __shfl_xor(cnt, off, 64);
    }
    if (lane == 0 && cnt) {
        atomicAdd(&locPart[b], sT);
        atomicAdd(&locPart[BB + b], sS);
        atomicAdd(&numpos[b], cnt);
    }
}

// ---------- kernel C: hard-negative mining (radix select) + fused finalize ----------
// grid = (2, BB): blockIdx.x selects tensor (0=T -> acc[2], 1=S -> acc[3]).
// Key = (v < 0) ? 0 : bits(v): encoded positives participate as 0.0, bit-exactly
// the reference's where(pos, 0, lc) ranking multiset (lc >= 0 always; sum of
// top-k is tie-order independent).
// Per-wave private histograms cap hot-bin atomic serialization at 64-way.
// Suffix scan is a 2-barrier wave shuffle scan.
// The last block to finish (device atomic counter) computes out[] (kD fused).
__global__ __launch_bounds__(1024) void kC(const float* __restrict__ lcT,
                                           const float* __restrict__ lcS,
                                           const int* __restrict__ numpos,
                                           const float* __restrict__ locPart,
                                           float* acc, int* ctr,
                                           float* __restrict__ out) {
    __shared__ unsigned keys[PP];
    __shared__ int whist[16 * 256];
    __shared__ int hist[256];
    __shared__ float fsb[16];
    __shared__ int isb[16];
    __shared__ int selBin, selAbove, lastFlag, wsum[4];
    int b = blockIdx.y;
    int tid = threadIdx.x;
    int lane = tid & 63;
    const float* src = ((blockIdx.x == 0) ? lcT : lcS) + (size_t)b * PP;

    float posSum = 0.0f;
    for (int i = tid; i < PP; i += 1024) {
        float v = src[i];
        keys[i] = (v < 0.0f) ? 0u : __float_as_uint(v);
        if (v < 0.0f) posSum += (-v - 1.0f);
    }
    posSum = blockReduceF(posSum, fsb);   // internal syncs fence keys[] writes

    int np = numpos[b];
    int k = min(3 * np, PP - 1);
    float mined = 0.0f;
    if (k > 0) {
        unsigned prefix = 0;
        int kk = k;
        int wid = tid >> 6;
        for (int round = 0; round < 4; ++round) {
            int shift = 24 - 8 * round;
            for (int i = tid; i < 16 * 256; i += 1024) whist[i] = 0;
            __syncthreads();
            for (int i = tid; i < PP; i += 1024) {
                unsigned key = keys[i];
                bool match = (round == 0) || ((key >> (shift + 8)) == prefix);
                if (match) atomicAdd(&whist[(wid << 8) | ((key >> shift) & 0xFF)], 1);
            }
            __syncthreads();
            if (tid < 256) {
                int h2 = 0;
                #pragma unroll
                for (int w = 0; w < 16; ++w) h2 += whist[(w << 8) | tid];
                hist[tid] = h2;
            }
            __syncthreads();
            // inclusive suffix scan of hist[256]: wave shuffle scan, 2 barriers.
            int x = (tid < 256) ? hist[tid] : 0;
            for (int d = 1; d < 64; d <<= 1) {
                int y = __shfl_down(x, d, 64);
                if (lane + d < 64) x += y;
            }
            if (tid < 256 && lane == 0) wsum[tid >> 6] = x;
            __syncthreads();
            if (tid < 256) {
                int wv = tid >> 6;
                int add = 0;
                if (wv < 3) add += wsum[wv + 1];
                if (wv < 2) add += wsum[wv + 2];
                if (wv < 1) add += wsum[wv + 3];
                int sfx = x + add;                 // sum_{j>=tid} hist[j]
                hist[tid] = sfx;
            }
            __syncthreads();
            if (tid < 256) {
                int above = (tid < 255) ? hist[tid + 1] : 0;
                if (above < kk && hist[tid] >= kk) {   // unique bin
                    selBin = tid;
                    selAbove = above;
                }
            }
            __syncthreads();
            prefix = (prefix << 8) | (unsigned)selBin;
            kk -= selAbove;
            __syncthreads();
        }
        // prefix = bit pattern of the exact k-th largest key
        int c = 0;
        float s = 0.0f;
        for (int i = tid; i < PP; i += 1024) {
            unsigned key = keys[i];
            if (key > prefix) { c += 1; s += __uint_as_float(key); }
        }
        c = blockReduceI(c, isb);
        s = blockReduceF(s, fsb);
        mined = s + (float)(k - c) * __uint_as_float(prefix);
    }
    if (tid == 0) {
        atomicAdd(&acc[(blockIdx.x == 0) ? 2 : 3], posSum + mined);
        __threadfence();                       // our acc write visible before ctr
        int old = atomicAdd(ctr, 1);           // device-scope
        lastFlag = (old == 2 * BB - 1) ? 1 : 0;
    }
    __syncthreads();
    if (lastFlag) {                            // fused finalize: last block
        __threadfence();
        int v = 0;
        float pT = 0.0f, pS = 0.0f;
        if (tid < BB) {
            v  = __hip_atomic_load(&numpos[tid], __ATOMIC_RELAXED, __HIP_MEMORY_SCOPE_AGENT);
            pT = __hip_atomic_load(&locPart[tid], __ATOMIC_RELAXED, __HIP_MEMORY_SCOPE_AGENT);
            pS = __hip_atomic_load(&locPart[BB + tid], __ATOMIC_RELAXED, __HIP_MEMORY_SCOPE_AGENT);
        }
        if (tid < 64) {
            for (int off = 32; off; off >>= 1) {
                v  += __shfl_xor(v,  off, 64);
                pT += __shfl_xor(pT, off, 64);
                pS += __shfl_xor(pS, off, 64);
            }
        }
        if (tid == 0) {
            float N = (float)v;
            float a2 = __hip_atomic_load(&acc[2], __ATOMIC_RELAXED, __HIP_MEMORY_SCOPE_AGENT);
            float a3 = __hip_atomic_load(&acc[3], __ATOMIC_RELAXED, __HIP_MEMORY_SCOPE_AGENT);
            out[0] = pT / N;  // loss_lT / N
            out[1] = a2 / N;  // loss_cT / N
            out[2] = pS / N;  // loss_lS / N
            out[3] = a3 / N;  // loss_cS / N
        }
    }
}

// ---------- launch ----------
extern "C" void kernel_launch(void* const* d_in, const int* in_sizes, int n_in,
                              void* d_out, int out_size, void* d_ws, size_t ws_size,
                              hipStream_t stream) {
    const float* locT  = (const float*)d_in[0];
    const float* confT = (const float*)d_in[1];
    const float* locS  = (const float*)d_in[2];
    const float* confS = (const float*)d_in[3];
    const float* loct  = (const float*)d_in[4];
    const int*   conft = (const int*)d_in[5];
    float* out = (float*)d_out;

    float* lcT = (float*)d_ws;
    float* lcS = lcT + (size_t)BB * PP;
    float* acc = lcS + (size_t)BB * PP;
    int* numpos = (int*)(acc + 4);
    int* ctr = numpos + BB;
    float* locPart = (float*)(ctr + 1);

    kInit<<<1, 64, 0, stream>>>(acc, numpos, ctr, locPart);

    dim3 gS((PP + ROWS_PB - 1) / ROWS_PB, BB);      // (137, 64)
    kStream<<<gS, 256, 0, stream>>>(confT, confS, conft,
                                    (const float4*)locT, (const float4*)locS,
                                    (const float4*)loct, lcT, lcS,
                                    locPart, numpos);

    dim3 gC(2, BB);
    kC<<<gC, 1024, 0, stream>>>(lcT, lcS, numpos, locPart, acc, ctr, out);
}